// Round 12
// baseline (90.102 us; speedup 1.0000x reference)
//
#include <hip/hip_runtime.h>
#include <hip/hip_fp16.h>
#include <math.h>

#define N_    8
#define H_    32
#define W_    32
#define C_    32
#define COUT_ 64
#define HO_   30
#define WO_   30
#define CSTR  20                  // dwords per (row,col) cell: 16 half2 pairs + 4 pad
#define NCOLS 34                  // 32 cols + 2 clamped halo (kills in-loop clamp)
#define SSTR  (3 * NCOLS * CSTR)  // 2040 dwords per sign plane
#define EK_DWORDS 18432           // 9 ij * 32 cog * 2 kern * 2 co2 * 16 cpair

// packed fp16 ops (2 elems/instr) — inline asm (ROCm 7.2 lacks __hmul2/__hmax2 here)
__device__ __forceinline__ unsigned pkmul16(unsigned a, unsigned b) {
    unsigned d; asm("v_pk_mul_f16 %0,%1,%2" : "=v"(d) : "v"(a), "v"(b)); return d;
}
__device__ __forceinline__ unsigned pkmax16(unsigned a, unsigned b) {
    unsigned d; asm("v_pk_max_f16 %0,%1,%2" : "=v"(d) : "v"(a), "v"(b)); return d;
}
__device__ __forceinline__ unsigned h2pack(float a, float b) {
    __half2 h = __halves2half2(__float2half(a), __float2half(b));
    return *reinterpret_cast<unsigned*>(&h);
}
__device__ __forceinline__ float h2red(unsigned u) {   // max(lo, hi)
    union { unsigned u; __half2 h; } c; c.u = u;
    return fmaxf(__low2float(c.h), __high2float(c.h));
}

// exp(k) as fp16 pairs, layout [ij(9)][cog(32)][kern(2)][co2(2)][cpair(16)]:
// wave cog's per-ij block = 64 contiguous dwords (uniform -> s_load).
__global__ void ek_kernel(const float* __restrict__ k1,
                          const float* __restrict__ k2,
                          unsigned* __restrict__ ekb) {
    int tid = blockIdx.x * 256 + threadIdx.x;
    if (tid >= EK_DWORDS) return;
    int cpair = tid & 15;
    int co2   = (tid >> 4) & 1;
    int kern  = (tid >> 5) & 1;
    int cog   = (tid >> 6) & 31;
    int ij    = tid >> 11;
    int co = cog * 2 + co2;
    int p0 = ij * 32 + cpair * 2;
    const float* s = kern ? k2 : k1;
    float f0 = expf(s[(size_t)p0 * COUT_ + co]);
    float f1 = expf(s[(size_t)(p0 + 1) * COUT_ + co]);
    ekb[tid] = h2pack(f0, f1);
}

// Fallback (ws too small): naive but correct.
__global__ void naive_kernel(const float* __restrict__ x,
                             const float* __restrict__ k1,
                             const float* __restrict__ k2,
                             const float* __restrict__ bias,
                             float* __restrict__ out) {
    int idx = blockIdx.x * 256 + threadIdx.x;
    if (idx >= N_ * HO_ * WO_ * COUT_) return;
    int co = idx & 63, pix = idx >> 6;
    int wo = pix % WO_, t = pix / WO_, ho = t % HO_, n = t / HO_;
    float m11 = 0, m12 = 0, m21 = 0, m22 = 0;
    for (int i = 0; i < 3; ++i)
        for (int j = 0; j < 3; ++j)
            for (int c = 0; c < 32; ++c) {
                float v  = x[((size_t)(n * H_ + ho + i) * W_ + wo + j) * C_ + c];
                float a1 = fmaxf(v, 0.1f), a2 = fmaxf(-v, 0.1f);
                int p = (i * 3 + j) * 32 + c;
                float q1 = __expf(k1[(size_t)p * 64 + co]);
                float q2 = __expf(k2[(size_t)p * 64 + co]);
                m11 = fmaxf(m11, a1 * q1); m12 = fmaxf(m12, a1 * q2);
                m21 = fmaxf(m21, a2 * q1); m22 = fmaxf(m22, a2 * q2);
            }
    out[idx] = m11 - m12 - m21 + m22 + bias[co];
}

// Block = (n, ho, oc): 4 waves; wave w owns co pair {cog*2, cog*2+1}, cog = oc*4+w.
// Lane = (hs, col): hs = sign half (0: a1-side m11,m12; 1: a2-side m21,m22),
// col = pixel column; each lane reduces all 32 c for its sign.
// k is wave-uniform -> SGPR operands via readfirstlane-derived pointer.
__global__ __launch_bounds__(256, 8)
void bmorph_kernel(const float* __restrict__ x,
                   const unsigned* __restrict__ ekb,
                   const float* __restrict__ bias,
                   float* __restrict__ out) {
    __shared__ unsigned ah[2 * SSTR];   // [sign][3 rows][34 cols][16 pairs + pad]

    const int b   = blockIdx.x;
    const int oc  = b & 7;
    const int ho  = (b >> 3) % HO_;
    const int n   = b / (8 * HO_);
    const int tid = threadIdx.x;

    // ---- stage a1/a2 fp16 pairs, 3 rows x 34 cols (clamped halo) ----
    const float* xsrc = x + (size_t)(n * H_ + ho) * (W_ * C_);
    for (int t = tid; t < 3 * NCOLS * 8; t += 256) {     // 816 float4 slots
        int c4 = t & 7;
        int cc = (t >> 3) % NCOLS;
        int r  = t / (NCOLS * 8);
        int cs = cc < W_ ? cc : W_ - 1;
        float4 v = *reinterpret_cast<const float4*>(xsrc + (size_t)((r * W_ + cs) * C_ + c4 * 4));
        uint2 u1 = make_uint2(h2pack(fmaxf(v.x, 0.1f), fmaxf(v.y, 0.1f)),
                              h2pack(fmaxf(v.z, 0.1f), fmaxf(v.w, 0.1f)));
        uint2 u2 = make_uint2(h2pack(fmaxf(-v.x, 0.1f), fmaxf(-v.y, 0.1f)),
                              h2pack(fmaxf(-v.z, 0.1f), fmaxf(-v.w, 0.1f)));
        int d = (r * NCOLS + cc) * CSTR + c4 * 2;
        *reinterpret_cast<uint2*>(ah + d)        = u1;
        *reinterpret_cast<uint2*>(ah + SSTR + d) = u2;
    }
    __syncthreads();

    const int w    = tid >> 6;
    const int lane = tid & 63;
    const int hs   = lane >> 5;
    const int col  = lane & 31;
    const int cog  = __builtin_amdgcn_readfirstlane(oc * 4 + w);   // uniform
    const unsigned* abase = ah + hs * SSTR;

    unsigned acc00 = 0u;   // co2=0, kern=0
    unsigned acc01 = 0u;   // co2=0, kern=1
    unsigned acc10 = 0u;   // co2=1, kern=0
    unsigned acc11 = 0u;   // co2=1, kern=1

    #pragma unroll 1
    for (int ij = 0; ij < 9; ++ij) {
        const int i_ = ij / 3;
        const int j_ = ij - i_ * 3;
        const unsigned* K = ekb + (size_t)(ij * 32 + cog) * 64;   // uniform ptr
        const unsigned* ap = abase + (i_ * NCOLS + col + j_) * CSTR;
        uint4 Aa = *reinterpret_cast<const uint4*>(ap);
        uint4 Ab = *reinterpret_cast<const uint4*>(ap + 4);
        uint4 Ac = *reinterpret_cast<const uint4*>(ap + 8);
        uint4 Ad = *reinterpret_cast<const uint4*>(ap + 12);

        // K index: kern*32 + co2*16 + q
        #define QSTEP(q, aq)                                          \
            acc00 = pkmax16(acc00, pkmul16(aq, K[q]));                \
            acc10 = pkmax16(acc10, pkmul16(aq, K[16 + q]));           \
            acc01 = pkmax16(acc01, pkmul16(aq, K[32 + q]));           \
            acc11 = pkmax16(acc11, pkmul16(aq, K[48 + q]));
        QSTEP(0,  Aa.x) QSTEP(1,  Aa.y) QSTEP(2,  Aa.z) QSTEP(3,  Aa.w)
        QSTEP(4,  Ab.x) QSTEP(5,  Ab.y) QSTEP(6,  Ab.z) QSTEP(7,  Ab.w)
        QSTEP(8,  Ac.x) QSTEP(9,  Ac.y) QSTEP(10, Ac.z) QSTEP(11, Ac.w)
        QSTEP(12, Ad.x) QSTEP(13, Ad.y) QSTEP(14, Ad.z) QSTEP(15, Ad.w)
        #undef QSTEP
    }

    // ---- combine: hs=0 has (m11,m12), hs=1 has (m21,m22) for same (col, co2) ----
    float sA = h2red(acc00) - h2red(acc01);   // hs=0: m11-m12 ; hs=1: m21-m22
    float sB = h2red(acc10) - h2red(acc11);
    float pA = __shfl_xor(sA, 32);
    float pB = __shfl_xor(sB, 32);
    if (hs == 0 && col < WO_) {
        const int cobase = cog * 2;
        float2 r = make_float2(sA - pA + bias[cobase],
                               sB - pB + bias[cobase + 1]);
        *reinterpret_cast<float2*>(
            out + ((size_t)(n * HO_ + ho) * WO_ + col) * COUT_ + cobase) = r;
    }
}

extern "C" void kernel_launch(void* const* d_in, const int* in_sizes, int n_in,
                              void* d_out, int out_size, void* d_ws, size_t ws_size,
                              hipStream_t stream) {
    const float* x    = (const float*)d_in[0];
    const float* k1   = (const float*)d_in[1];
    const float* k2   = (const float*)d_in[2];
    const float* bias = (const float*)d_in[3];
    float* out = (float*)d_out;

    const size_t ek_bytes = (size_t)EK_DWORDS * sizeof(unsigned);   // 73728

    if (ws_size >= ek_bytes) {
        unsigned* ekb = (unsigned*)d_ws;
        ek_kernel<<<(EK_DWORDS + 255) / 256, 256, 0, stream>>>(k1, k2, ekb);
        bmorph_kernel<<<N_ * HO_ * 8, 256, 0, stream>>>(x, ekb, bias, out);
    } else {
        int tot = N_ * HO_ * WO_ * COUT_;
        naive_kernel<<<(tot + 255) / 256, 256, 0, stream>>>(x, k1, k2, bias, out);
    }
}

// Round 15
// 83.983 us; speedup vs baseline: 1.0729x; 1.0729x over previous
//
#include <hip/hip_runtime.h>
#include <hip/hip_fp16.h>
#include <math.h>

#define N_    8
#define H_    32
#define W_    32
#define C_    32
#define COUT_ 64
#define HO_   30
#define WO_   30
#define CSTR  20                  // dwords per (row,col) cell: 16 half2 pairs + 4 pad
#define NCOLS 34                  // 32 cols + 2 clamped halo (kills in-loop clamp)
#define SSTR  (3 * NCOLS * CSTR)  // 2040 dwords per sign plane
#define EK_DWORDS 18432           // 9 ij * 32 cog * 2 kern * 2 co2 * 16 cpair

// packed fp16 ops. pkmul16s: K operand in SGPR (VOP3P allows one scalar src) --
// this is the whole point of the SGPR-K design: zero v_mov, zero K-LDS.
__device__ __forceinline__ unsigned pkmul16s(unsigned a, unsigned k) {
    unsigned d; asm("v_pk_mul_f16 %0,%1,%2" : "=v"(d) : "v"(a), "s"(k)); return d;
}
__device__ __forceinline__ unsigned pkmax16(unsigned a, unsigned b) {
    unsigned d; asm("v_pk_max_f16 %0,%1,%2" : "=v"(d) : "v"(a), "v"(b)); return d;
}
__device__ __forceinline__ unsigned h2pack(float a, float b) {
    __half2 h = __halves2half2(__float2half(a), __float2half(b));
    return *reinterpret_cast<unsigned*>(&h);
}
__device__ __forceinline__ float h2red(unsigned u) {   // max(lo, hi)
    union { unsigned u; __half2 h; } c; c.u = u;
    return fmaxf(__low2float(c.h), __high2float(c.h));
}

// exp(k) as fp16 pairs, layout [ij(9)][cog(32)][kern(2)][co2(2)][cpair(16)]:
// wave cog's per-ij block = 64 contiguous dwords (uniform -> s_load_dwordx16 x4).
__global__ void ek_kernel(const float* __restrict__ k1,
                          const float* __restrict__ k2,
                          unsigned* __restrict__ ekb) {
    int tid = blockIdx.x * 256 + threadIdx.x;
    if (tid >= EK_DWORDS) return;
    int cpair = tid & 15;
    int co2   = (tid >> 4) & 1;
    int kern  = (tid >> 5) & 1;
    int cog   = (tid >> 6) & 31;
    int ij    = tid >> 11;
    int co = cog * 2 + co2;
    int p0 = ij * 32 + cpair * 2;
    const float* s = kern ? k2 : k1;
    float f0 = expf(s[(size_t)p0 * COUT_ + co]);
    float f1 = expf(s[(size_t)(p0 + 1) * COUT_ + co]);
    ekb[tid] = h2pack(f0, f1);
}

// Fallback (ws too small): naive but correct.
__global__ void naive_kernel(const float* __restrict__ x,
                             const float* __restrict__ k1,
                             const float* __restrict__ k2,
                             const float* __restrict__ bias,
                             float* __restrict__ out) {
    int idx = blockIdx.x * 256 + threadIdx.x;
    if (idx >= N_ * HO_ * WO_ * COUT_) return;
    int co = idx & 63, pix = idx >> 6;
    int wo = pix % WO_, t = pix / WO_, ho = t % HO_, n = t / HO_;
    float m11 = 0, m12 = 0, m21 = 0, m22 = 0;
    for (int i = 0; i < 3; ++i)
        for (int j = 0; j < 3; ++j)
            for (int c = 0; c < 32; ++c) {
                float v  = x[((size_t)(n * H_ + ho + i) * W_ + wo + j) * C_ + c];
                float a1 = fmaxf(v, 0.1f), a2 = fmaxf(-v, 0.1f);
                int p = (i * 3 + j) * 32 + c;
                float q1 = __expf(k1[(size_t)p * 64 + co]);
                float q2 = __expf(k2[(size_t)p * 64 + co]);
                m11 = fmaxf(m11, a1 * q1); m12 = fmaxf(m12, a1 * q2);
                m21 = fmaxf(m21, a2 * q1); m22 = fmaxf(m22, a2 * q2);
            }
    out[idx] = m11 - m12 - m21 + m22 + bias[co];
}

// Block = (n, ho, oc): 4 waves; wave w owns co pair {cog*2, cog*2+1}, cog = oc*4+w.
// Lane = (hs, col): hs = sign half (0: m11,m12; 1: m21,m22), col = pixel column.
// K lives in SGPRs (s_load via uniform address), consumed directly as the
// scalar operand of v_pk_mul_f16. Hot loop: 4 LDS b128 + 128 pk VALU per ij.
__global__ __launch_bounds__(256, 8)
void bmorph_kernel(const float* __restrict__ x,
                   const unsigned* __restrict__ ekb,
                   const float* __restrict__ bias,
                   float* __restrict__ out) {
    __shared__ unsigned ah[2 * SSTR];   // [sign][3 rows][34 cols][16 pairs + pad]

    const int b   = blockIdx.x;
    const int oc  = b & 7;
    const int ho  = (b >> 3) % HO_;
    const int n   = b / (8 * HO_);
    const int tid = threadIdx.x;

    // ---- stage a1/a2 fp16 pairs, 3 rows x 34 cols (clamped halo) ----
    const float* xsrc = x + (size_t)(n * H_ + ho) * (W_ * C_);
    for (int t = tid; t < 3 * NCOLS * 8; t += 256) {     // 816 float4 slots
        int c4 = t & 7;
        int cc = (t >> 3) % NCOLS;
        int r  = t / (NCOLS * 8);
        int cs = cc < W_ ? cc : W_ - 1;
        float4 v = *reinterpret_cast<const float4*>(xsrc + (size_t)((r * W_ + cs) * C_ + c4 * 4));
        uint2 u1 = make_uint2(h2pack(fmaxf(v.x, 0.1f), fmaxf(v.y, 0.1f)),
                              h2pack(fmaxf(v.z, 0.1f), fmaxf(v.w, 0.1f)));
        uint2 u2 = make_uint2(h2pack(fmaxf(-v.x, 0.1f), fmaxf(-v.y, 0.1f)),
                              h2pack(fmaxf(-v.z, 0.1f), fmaxf(-v.w, 0.1f)));
        int d = (r * NCOLS + cc) * CSTR + c4 * 2;
        *reinterpret_cast<uint2*>(ah + d)        = u1;
        *reinterpret_cast<uint2*>(ah + SSTR + d) = u2;
    }
    __syncthreads();

    const int w    = tid >> 6;
    const int lane = tid & 63;
    const int hs   = lane >> 5;
    const int col  = lane & 31;
    const int cog  = __builtin_amdgcn_readfirstlane(oc * 4 + w);   // uniform (SGPR)
    const unsigned* abase = ah + hs * SSTR;

    unsigned acc00 = 0u;   // co2=0, kern=0
    unsigned acc01 = 0u;   // co2=0, kern=1
    unsigned acc10 = 0u;   // co2=1, kern=0
    unsigned acc11 = 0u;   // co2=1, kern=1

    #pragma unroll 1
    for (int ij = 0; ij < 9; ++ij) {
        const int i_ = ij / 3;
        const int j_ = ij - i_ * 3;
        const unsigned* K = ekb + (size_t)(ij * 32 + cog) * 64;   // uniform ptr -> s_load
        const unsigned* ap = abase + (i_ * NCOLS + col + j_) * CSTR;
        uint4 Aa = *reinterpret_cast<const uint4*>(ap);
        uint4 Ab = *reinterpret_cast<const uint4*>(ap + 4);
        uint4 Ac = *reinterpret_cast<const uint4*>(ap + 8);
        uint4 Ad = *reinterpret_cast<const uint4*>(ap + 12);

        // K index: kern*32 + co2*16 + q ; K operand rides the scalar port
        #define QSTEP(q, aq)                                          \
            acc00 = pkmax16(acc00, pkmul16s(aq, K[q]));               \
            acc10 = pkmax16(acc10, pkmul16s(aq, K[16 + q]));          \
            acc01 = pkmax16(acc01, pkmul16s(aq, K[32 + q]));          \
            acc11 = pkmax16(acc11, pkmul16s(aq, K[48 + q]));
        QSTEP(0,  Aa.x) QSTEP(1,  Aa.y) QSTEP(2,  Aa.z) QSTEP(3,  Aa.w)
        QSTEP(4,  Ab.x) QSTEP(5,  Ab.y) QSTEP(6,  Ab.z) QSTEP(7,  Ab.w)
        QSTEP(8,  Ac.x) QSTEP(9,  Ac.y) QSTEP(10, Ac.z) QSTEP(11, Ac.w)
        QSTEP(12, Ad.x) QSTEP(13, Ad.y) QSTEP(14, Ad.z) QSTEP(15, Ad.w)
        #undef QSTEP
    }

    // ---- combine: hs=0 has (m11,m12), hs=1 has (m21,m22) for same (col, co2) ----
    float sA = h2red(acc00) - h2red(acc01);   // hs=0: m11-m12 ; hs=1: m21-m22
    float sB = h2red(acc10) - h2red(acc11);
    float pA = __shfl_xor(sA, 32);
    float pB = __shfl_xor(sB, 32);
    if (hs == 0 && col < WO_) {
        const int cobase = cog * 2;
        float2 r = make_float2(sA - pA + bias[cobase],
                               sB - pB + bias[cobase + 1]);
        *reinterpret_cast<float2*>(
            out + ((size_t)(n * HO_ + ho) * WO_ + col) * COUT_ + cobase) = r;
    }
}

extern "C" void kernel_launch(void* const* d_in, const int* in_sizes, int n_in,
                              void* d_out, int out_size, void* d_ws, size_t ws_size,
                              hipStream_t stream) {
    const float* x    = (const float*)d_in[0];
    const float* k1   = (const float*)d_in[1];
    const float* k2   = (const float*)d_in[2];
    const float* bias = (const float*)d_in[3];
    float* out = (float*)d_out;

    const size_t ek_bytes = (size_t)EK_DWORDS * sizeof(unsigned);   // 73728

    if (ws_size >= ek_bytes) {
        unsigned* ekb = (unsigned*)d_ws;
        ek_kernel<<<(EK_DWORDS + 255) / 256, 256, 0, stream>>>(k1, k2, ekb);
        bmorph_kernel<<<N_ * HO_ * 8, 256, 0, stream>>>(x, ekb, bias, out);
    } else {
        int tot = N_ * HO_ * WO_ * COUT_;
        naive_kernel<<<(tot + 255) / 256, 256, 0, stream>>>(x, k1, k2, bias, out);
    }
}